// Round 14
// baseline (390.890 us; speedup 1.0000x reference)
//
#include <hip/hip_runtime.h>
#include <stdint.h>
#include <stddef.h>

// ---------------------------------------------------------------------------
// HHGNN. R14 = INSTRUMENTATION round on the R13 structure (167.6us ~= R10
// champion). 13 rounds of GEMM levers moved nothing; k2/k3 counters have
// never been visible (harness fills ~150-160us own the top-5). This round
// replica-triples k2 (grid 1536) and k3 (grid 3072) so both exceed the
// fills and surface with full PMC rows. Replicas are REPLICA-MAJOR in bid
// (rho = bid/512 resp /1024) so they execute as sequential GPU waves:
// no fake L3 reuse (268MB adj > 256MB L3 evicts between waves), dur ~= 3x,
// FETCH ~= 3x. Replica blocks write byte-identical outputs (idempotent).
// Champion structure is unchanged and restored next round with the fix the
// counters indicate.
// ws: xT 8.39 + latT 4.19 + WT 0.43 = 13.0MB.
// ---------------------------------------------------------------------------

typedef float    f32x4_t  __attribute__((ext_vector_type(4)));
typedef __bf16   bf16x8_t __attribute__((ext_vector_type(8)));
typedef unsigned int u32x4_t __attribute__((ext_vector_type(4)));
typedef unsigned int u32x2_t __attribute__((ext_vector_type(2)));

__device__ __forceinline__ unsigned short f2bf(float f) {
    union { float f; unsigned int u; } v; v.f = f;
    unsigned int u = v.u;
    return (unsigned short)((u + 0x7FFFu + ((u >> 16) & 1u)) >> 16);
}

__device__ __forceinline__ unsigned int cvtpk(float a, float b) {
    unsigned int r;
    asm("v_cvt_pk_bf16_f32 %0, %1, %2" : "=v"(r) : "v"(a), "v"(b));
    return r;
}

__device__ __forceinline__ bool mask_on(const unsigned char* m, int gid) {
    return (m[gid] | m[(gid >> 2) << 2]) != 0;
}

__device__ __forceinline__ int foff(int row, int g) {
    return row * 128 + (((g) ^ (row & 7)) << 4);
}
__device__ __forceinline__ int foff128(int row, int g) {
    return row * 256 + (((g) ^ (row & 15)) << 4);
}

template<int GSTRIDE>
__device__ __forceinline__ void stage_B(const unsigned short* __restrict__ gb,
                                        int k0, unsigned short* ldsB, int t)
{
    const int l = t & 63, w = t >> 6;
    const int hsub = l >> 3;
    const int csrc = ((l & 7) ^ hsub) << 3;
    #pragma unroll
    for (int i = 0; i < 4; ++i) {
        const int hbase = i * 32 + w * 8;
        const unsigned short* src = gb + (size_t)(hbase + hsub) * GSTRIDE + k0 + csrc;
        unsigned short* dst = ldsB + hbase * 64;
        __builtin_amdgcn_global_load_lds(
            (__attribute__((address_space(1))) void*)src,
            (__attribute__((address_space(3))) void*)dst, 16, 0, 0);
    }
}

template<int GSTRIDE>
__device__ __forceinline__ void stage_B128(const unsigned short* __restrict__ gb,
                                           int k0, unsigned short* ldsB, int t)
{
    const int l = t & 63, w = t >> 6;
    const int rsub = l >> 4;
    #pragma unroll
    for (int i = 0; i < 8; ++i) {
        const int rbase = w * 32 + i * 4;
        const int row = rbase + rsub;
        const int csrc = (((l & 15) ^ (row & 15)) << 3);
        const unsigned short* src = gb + (size_t)row * GSTRIDE + k0 + csrc;
        unsigned short* dst = ldsB + rbase * 128;
        __builtin_amdgcn_global_load_lds(
            (__attribute__((address_space(1))) void*)src,
            (__attribute__((address_space(3))) void*)dst, 16, 0, 0);
    }
}

// ---------------------------------------------------------------------------
// k0: WT[t][d][h] = bf16(W[t][h][d])
// ---------------------------------------------------------------------------
__global__ __launch_bounds__(256) void k0_wtrans(
    const float* __restrict__ W, unsigned short* __restrict__ WT)
{
    __shared__ float tile[128][132];
    const int t = threadIdx.x, ty = blockIdx.x;
    const float* Wt = W + (size_t)ty * 128 * 128;
    for (int it = 0; it < 16; ++it) {
        int idx = it * 256 + t;
        int h = idx >> 5, c = (idx & 31) * 4;
        *(float4*)(&tile[h][c]) = *(const float4*)(Wt + h * 128 + c);
    }
    __syncthreads();
    const int d = t >> 1, half = t & 1, h0 = half * 64;
    unsigned short* out = WT + ((size_t)ty * 128 + d) * 128 + h0;
    #pragma unroll
    for (int ch = 0; ch < 8; ++ch) {
        int h = h0 + ch * 8;
        u32x4_t o;
        o[0] = cvtpk(tile[h + 0][d], tile[h + 1][d]);
        o[1] = cvtpk(tile[h + 2][d], tile[h + 3][d]);
        o[2] = cvtpk(tile[h + 4][d], tile[h + 5][d]);
        o[3] = cvtpk(tile[h + 6][d], tile[h + 7][d]);
        *(u32x4_t*)(out + ch * 8) = o;
    }
}

// ---------------------------------------------------------------------------
// k1: typed linear (MFMA) + bias + mask + LayerNorm -> xT bf16 [B][H][N]
// (unchanged from R10)
// ---------------------------------------------------------------------------
__global__ __launch_bounds__(256) void k1_typed_ln(
    const float* __restrict__ embeds,
    const int*   __restrict__ ntype,
    const unsigned char* __restrict__ mask8,
    const unsigned short* __restrict__ WT,
    const float* __restrict__ bias,
    const float* __restrict__ gamma,
    const float* __restrict__ beta,
    unsigned short* __restrict__ xT)
{
    __shared__ unsigned short e_lds[64][136];
    __shared__ unsigned short y_lds[64][136];
    __shared__ unsigned short lists[13][64];
    __shared__ int cnt[13];
    __shared__ int grp_ty[32], grp_base[32], grp_n;
    __shared__ unsigned char msk[64];
    __shared__ float g_lds[128], be_lds[128];

    const int t   = threadIdx.x;
    const int bid = blockIdx.x;
    const int b   = bid & 7;
    const int n0  = (bid >> 3) << 6;
    const int gbase = b * 4096 + n0;
    const float* ebase = embeds + (size_t)gbase * 128;

    {
        const int n = t >> 2, q = t & 3;
        const float* src = ebase + n * 128 + q * 32;
        #pragma unroll
        for (int c = 0; c < 4; ++c) {
            f32x4_t va = *(const f32x4_t*)(src + c * 8);
            f32x4_t vb = *(const f32x4_t*)(src + c * 8 + 4);
            u32x4_t o;
            o[0] = cvtpk(va[0], va[1]); o[1] = cvtpk(va[2], va[3]);
            o[2] = cvtpk(vb[0], vb[1]); o[3] = cvtpk(vb[2], vb[3]);
            *(u32x4_t*)(&e_lds[n][q * 32 + c * 8]) = o;
        }
    }
    if (t < 128) { g_lds[t] = gamma[t]; be_lds[t] = beta[t]; }
    if (t < 64)  msk[t] = mask_on(mask8, gbase + t) ? 1 : 0;
    if (t < 13)  cnt[t] = 0;
    __syncthreads();

    if (t < 64) {
        int ty = ntype[(size_t)gbase + t];
        int slot = atomicAdd(&cnt[ty], 1);
        lists[ty][slot] = (unsigned short)t;
    }
    __syncthreads();
    if (t == 0) {
        int g = 0;
        for (int ty = 0; ty < 13; ++ty) {
            int c = cnt[ty];
            for (int base = 0; base < c; base += 16) {
                grp_ty[g] = ty; grp_base[g] = base; ++g;
            }
        }
        grp_n = g;
    }
    __syncthreads();

    const int NG   = grp_n;
    const int lane = t & 63, wv = t >> 6;
    const int fr = lane & 15, fg = lane >> 4;
    const int d0 = wv * 32;

    for (int g = 0; g < NG; ++g) {
        const int ty = grp_ty[g], base = grp_base[g];
        const int cend = cnt[ty] - 1;
        const int nodeA = lists[ty][min(base + fr, cend)];

        bf16x8_t afr[4];
        #pragma unroll
        for (int kk = 0; kk < 4; ++kk)
            afr[kk] = __builtin_bit_cast(bf16x8_t,
                *(const u32x4_t*)(&e_lds[nodeA][kk * 32 + fg * 8]));

        const unsigned short* wt = WT + (size_t)ty * 128 * 128;
        f32x4_t acc0 = f32x4_t{0.f, 0.f, 0.f, 0.f};
        f32x4_t acc1 = f32x4_t{0.f, 0.f, 0.f, 0.f};
        #pragma unroll
        for (int kk = 0; kk < 4; ++kk) {
            bf16x8_t b0 = __builtin_bit_cast(bf16x8_t,
                *(const u32x4_t*)(wt + (size_t)(d0 + fr) * 128 + kk * 32 + fg * 8));
            bf16x8_t b1 = __builtin_bit_cast(bf16x8_t,
                *(const u32x4_t*)(wt + (size_t)(d0 + 16 + fr) * 128 + kk * 32 + fg * 8));
            acc0 = __builtin_amdgcn_mfma_f32_16x16x32_bf16(afr[kk], b0, acc0, 0, 0, 0);
            acc1 = __builtin_amdgcn_mfma_f32_16x16x32_bf16(afr[kk], b1, acc1, 0, 0, 0);
        }

        const float bs0 = bias[ty * 128 + d0 + fr];
        const float bs1 = bias[ty * 128 + d0 + 16 + fr];
        #pragma unroll
        for (int j = 0; j < 4; ++j) {
            const int nd = lists[ty][min(base + fg * 4 + j, cend)];
            if (msk[nd]) {
                y_lds[nd][d0 + fr]      = f2bf(acc0[j] + bs0);
                y_lds[nd][d0 + 16 + fr] = f2bf(acc1[j] + bs1);
            } else {
                y_lds[nd][d0 + fr]      = e_lds[nd][d0 + fr];
                y_lds[nd][d0 + 16 + fr] = e_lds[nd][d0 + 16 + fr];
            }
        }
    }
    __syncthreads();

    for (int i = 0; i < 16; ++i) {
        const int n = wv + i * 4;
        unsigned int u = *(const unsigned int*)(&y_lds[n][lane * 2]);
        float vx = __builtin_bit_cast(float, u << 16);
        float vy = __builtin_bit_cast(float, u & 0xffff0000u);
        float s = vx + vy;
        float q = vx * vx + vy * vy;
        #pragma unroll
        for (int mw = 32; mw >= 1; mw >>= 1) {
            s += __shfl_xor(s, mw);
            q += __shfl_xor(q, mw);
        }
        const float mu  = s * 0.0078125f;
        const float var = q * 0.0078125f - mu * mu;
        const float r   = rsqrtf(var + 1e-5f);
        const float ox = (vx - mu) * r * g_lds[lane * 2]     + be_lds[lane * 2];
        const float oy = (vy - mu) * r * g_lds[lane * 2 + 1] + be_lds[lane * 2 + 1];
        *(unsigned int*)(&y_lds[n][lane * 2]) = cvtpk(ox, oy);
    }
    __syncthreads();

    const int nl = t & 63, hg = t >> 6;
    unsigned short* xrow = xT + (size_t)b * 128 * 4096 + n0 + nl;
    for (int i = 0; i < 32; ++i) {
        const int h = hg * 32 + i;
        xrow[(size_t)h * 4096] = y_lds[nl][h];
    }
}

// ---------------------------------------------------------------------------
// Kernel 2: latT[b][h][m] = sum_n adj[b][n][m] * x[b][n][h]
// R13 kernel; grid 1536 = 3 replicas x 512 (replica-major). Replicas
// recompute identical outputs (idempotent) so rocprof sees k2 at ~3x dur.
// ---------------------------------------------------------------------------
__global__ __launch_bounds__(256) void k2_lat(
    const float* __restrict__ adj,
    const unsigned short* __restrict__ xT,
    unsigned short* __restrict__ latT)
{
    __shared__ unsigned short Al[2][32 * 128];
    __shared__ unsigned short Bl[2][128 * 128];

    const int t   = threadIdx.x;
    const int orig = blockIdx.x & 511;          // replica rho = blockIdx.x >> 9
    const int b   = orig & 7;
    const int m0  = (orig >> 3) << 5;
    const float* adjb = adj + (size_t)b * 4096 * 2048;
    const unsigned short* xb = xT + (size_t)b * 128 * 4096;

    const int lane = t & 63, wv = t >> 6;
    const int wm = wv & 1, wh = wv >> 1;

    const int a_kp = t >> 2;        // n-pair 0..63
    const int a_m  = (t & 3) << 3;  // 8 m's

    const int fr = lane & 15, fg = lane >> 4;
    int offA[4], offB[4][4];
    #pragma unroll
    for (int kk = 0; kk < 4; ++kk) offA[kk] = foff128(wm * 16 + fr, kk * 4 + fg);
    #pragma unroll
    for (int j = 0; j < 4; ++j)
        #pragma unroll
        for (int kk = 0; kk < 4; ++kk)
            offB[j][kk] = foff128(wh * 64 + j * 16 + fr, kk * 4 + fg);

    f32x4_t ar0a, ar0b, ar1a, ar1b;
    auto LOAD_A = [&](int k0) {
        const float* p = adjb + (size_t)(k0 + a_kp * 2) * 2048 + m0 + a_m;
        ar0a = *(const f32x4_t*)(p);
        ar0b = *(const f32x4_t*)(p + 4);
        ar1a = *(const f32x4_t*)(p + 2048);
        ar1b = *(const f32x4_t*)(p + 2052);
    };
    auto WRITE_A = [&](int buf) {
        const int g = a_kp >> 2, wrd = a_kp & 3;
        unsigned int pk[8];
        pk[0] = cvtpk(ar0a[0], ar1a[0]); pk[1] = cvtpk(ar0a[1], ar1a[1]);
        pk[2] = cvtpk(ar0a[2], ar1a[2]); pk[3] = cvtpk(ar0a[3], ar1a[3]);
        pk[4] = cvtpk(ar0b[0], ar1b[0]); pk[5] = cvtpk(ar0b[1], ar1b[1]);
        pk[6] = cvtpk(ar0b[2], ar1b[2]); pk[7] = cvtpk(ar0b[3], ar1b[3]);
        #pragma unroll
        for (int j = 0; j < 8; ++j) {
            const int m = a_m + j;
            *(unsigned int*)((char*)(&Al[buf][0]) + m * 256
                + (((g ^ (m & 15)) & 15) << 4) + wrd * 4) = pk[j];
        }
    };

    f32x4_t acc[4];
    #pragma unroll
    for (int j = 0; j < 4; ++j) acc[j] = f32x4_t{0.f, 0.f, 0.f, 0.f};

    LOAD_A(0);
    stage_B128<4096>(xb, 0, &Bl[0][0], t);
    WRITE_A(0);
    __syncthreads();

    for (int s = 0; s < 32; ++s) {
        const int buf = s & 1;
        if (s < 31) {
            LOAD_A((s + 1) * 128);
            stage_B128<4096>(xb, (s + 1) * 128, &Bl[buf ^ 1][0], t);
        }
        bf16x8_t af[4];
        #pragma unroll
        for (int kk = 0; kk < 4; ++kk)
            af[kk] = __builtin_bit_cast(bf16x8_t,
                *(const u32x4_t*)((const char*)(&Al[buf][0]) + offA[kk]));
        #pragma unroll
        for (int j = 0; j < 4; ++j) {
            #pragma unroll
            for (int kk = 0; kk < 4; ++kk) {
                bf16x8_t bfj = __builtin_bit_cast(bf16x8_t,
                    *(const u32x4_t*)((const char*)(&Bl[buf][0]) + offB[j][kk]));
                acc[j] = __builtin_amdgcn_mfma_f32_16x16x32_bf16(af[kk], bfj, acc[j], 0, 0, 0);
            }
        }
        if (s < 31) WRITE_A(buf ^ 1);
        __syncthreads();
    }

    const int mrow = m0 + wm * 16 + (lane >> 4) * 4;
    #pragma unroll
    for (int j = 0; j < 4; ++j) {
        int col = wh * 64 + j * 16 + fr;
        unsigned int o0 = cvtpk(acc[j][0], acc[j][1]);
        unsigned int o1 = cvtpk(acc[j][2], acc[j][3]);
        unsigned int* dst = (unsigned int*)(latT + (size_t)(b * 128 + col) * 2048 + mrow);
        dst[0] = o0; dst[1] = o1;
    }
}

// ---------------------------------------------------------------------------
// Kernel 3: ret[b][n][h] = sum_m adj[b][n][m] * latT[b][h][m]
// R10 kernel; grid 3072 = 3 replicas x 1024 (replica-major), idempotent.
// ---------------------------------------------------------------------------
__global__ __launch_bounds__(256) void k3_ret(
    const float* __restrict__ adj,
    const unsigned short* __restrict__ latT,
    float* __restrict__ ret)
{
    __shared__ unsigned short Al[2][32 * 64];
    __shared__ unsigned short Bl[2][128 * 64];

    const int t   = threadIdx.x;
    const int orig = blockIdx.x & 1023;         // replica rho = blockIdx.x >> 10
    const int b   = orig & 7;
    const int n0  = (orig >> 3) << 5;
    const float* adjb = adj + (size_t)b * 4096 * 2048;
    const unsigned short* lb = latT + (size_t)b * 128 * 2048;

    const int lane = t & 63, wv = t >> 6;
    const int wn = wv & 1, wh = wv >> 1;

    const int a_r = t >> 3;
    const int a_c = t & 7;

    const int fr = lane & 15, fg = lane >> 4;
    int offA[2], offB[4][2];
    #pragma unroll
    for (int kk = 0; kk < 2; ++kk) offA[kk] = foff(wn * 16 + fr, kk * 4 + fg);
    #pragma unroll
    for (int j = 0; j < 4; ++j)
        #pragma unroll
        for (int kk = 0; kk < 2; ++kk)
            offB[j][kk] = foff(wh * 64 + j * 16 + fr, kk * 4 + fg);

    f32x4_t ar0, ar1;
    auto LOAD_A = [&](int k0) {
        const float* p = adjb + (size_t)(n0 + a_r) * 2048 + k0 + a_c * 8;
        ar0 = *(const f32x4_t*)(p);
        ar1 = *(const f32x4_t*)(p + 4);
    };
    auto WRITE_A = [&](int buf) {
        u32x4_t pk;
        pk[0] = cvtpk(ar0[0], ar0[1]);
        pk[1] = cvtpk(ar0[2], ar0[3]);
        pk[2] = cvtpk(ar1[0], ar1[1]);
        pk[3] = cvtpk(ar1[2], ar1[3]);
        *(u32x4_t*)((char*)(&Al[buf][0]) + a_r * 128 + ((a_c ^ (a_r & 7)) << 4)) = pk;
    };

    f32x4_t acc[4];
    #pragma unroll
    for (int j = 0; j < 4; ++j) acc[j] = f32x4_t{0.f, 0.f, 0.f, 0.f};

    LOAD_A(0);
    stage_B<2048>(lb, 0, &Bl[0][0], t);
    WRITE_A(0);
    __syncthreads();

    for (int s = 0; s < 32; ++s) {
        const int buf = s & 1;
        if (s < 31) {
            LOAD_A((s + 1) * 64);
            stage_B<2048>(lb, (s + 1) * 64, &Bl[buf ^ 1][0], t);
        }
        bf16x8_t af[2];
        #pragma unroll
        for (int kk = 0; kk < 2; ++kk)
            af[kk] = __builtin_bit_cast(bf16x8_t,
                *(const u32x4_t*)((const char*)(&Al[buf][0]) + offA[kk]));
        #pragma unroll
        for (int j = 0; j < 4; ++j) {
            #pragma unroll
            for (int kk = 0; kk < 2; ++kk) {
                bf16x8_t bfj = __builtin_bit_cast(bf16x8_t,
                    *(const u32x4_t*)((const char*)(&Bl[buf][0]) + offB[j][kk]));
                acc[j] = __builtin_amdgcn_mfma_f32_16x16x32_bf16(af[kk], bfj, acc[j], 0, 0, 0);
            }
        }
        if (s < 31) WRITE_A(buf ^ 1);
        __syncthreads();
    }

    const int nrow = n0 + wn * 16 + (lane >> 4) * 4;
    #pragma unroll
    for (int j = 0; j < 4; ++j) {
        int col = wh * 64 + j * 16 + fr;
        #pragma unroll
        for (int jj = 0; jj < 4; ++jj) {
            ret[((size_t)b * 4096 + nrow + jj) * 128 + col] = acc[j][jj];
        }
    }
}

// ---------------------------------------------------------------------------
extern "C" void kernel_launch(void* const* d_in, const int* in_sizes, int n_in,
                              void* d_out, int out_size, void* d_ws, size_t ws_size,
                              hipStream_t stream) {
    const float* adj    = (const float*)d_in[0];
    const float* embeds = (const float*)d_in[1];
    const int*   ntype  = (const int*)d_in[2];
    const unsigned char* mask8 = (const unsigned char*)d_in[3];
    const float* W      = (const float*)d_in[4];
    const float* bias   = (const float*)d_in[5];
    const float* gamma  = (const float*)d_in[6];
    const float* beta   = (const float*)d_in[7];
    float* ret = (float*)d_out;

    unsigned short* xT   = (unsigned short*)d_ws;                   // 8.39 MB
    unsigned short* latT = xT + (size_t)8 * 128 * 4096;             // 4.19 MB
    unsigned short* WT   = latT + (size_t)8 * 128 * 2048;           // 0.43 MB
    // ws needed: 13.0 MB

    hipLaunchKernelGGL(k0_wtrans, dim3(13), dim3(256), 0, stream, W, WT);
    hipLaunchKernelGGL(k1_typed_ln, dim3(512), dim3(256), 0, stream,
                       embeds, ntype, mask8, WT, bias, gamma, beta, xT);
    hipLaunchKernelGGL(k2_lat, dim3(1536), dim3(256), 0, stream, adj, xT, latT);
    hipLaunchKernelGGL(k3_ret, dim3(3072), dim3(256), 0, stream, adj, latT, ret);
}

// Round 16
// 186.465 us; speedup vs baseline: 2.0963x; 2.0963x over previous
//
#include <hip/hip_runtime.h>
#include <stdint.h>
#include <stddef.h>

// ---------------------------------------------------------------------------
// HHGNN. R16 vs R13/R10 (167us champion). R14 counters: k2 ~80us,
// Occupancy 19.6%, all pipes idle -> latency-bound at 2 blocks/CU
// (GRID-limited: 512 blocks, LDS 40KB would fit 4). R15's 8-wave rewrite
// NaN'd (discarded, unproven path). ONE lever, proven parts only:
// k2 split-K x2 — R10 k2 body byte-identical except (a) bid decomposes to
// (mtile, nc), (b) nbase=nc*2048 added to A-row/B-col k-offsets, (c) f32x4
// partial stores to pLat (R8 pattern), (d) tiny k2_red reduce (R3/R8
// pattern). grid 1024 -> 4 blocks/CU, 16 waves/CU = k3's occupancy (which
// sits at its floor). Extra traffic ~37MB ~= 6us.
// k0/k1/k3 byte-identical to R13 (k3 = R10-exact).
// ws: xT 8.39 + latT 4.19 + WT 0.43 + pLat 16.78 = 29.8MB.
// ---------------------------------------------------------------------------

typedef float    f32x4_t  __attribute__((ext_vector_type(4)));
typedef __bf16   bf16x8_t __attribute__((ext_vector_type(8)));
typedef unsigned int u32x4_t __attribute__((ext_vector_type(4)));
typedef unsigned int u32x2_t __attribute__((ext_vector_type(2)));

__device__ __forceinline__ unsigned short f2bf(float f) {
    union { float f; unsigned int u; } v; v.f = f;
    unsigned int u = v.u;
    return (unsigned short)((u + 0x7FFFu + ((u >> 16) & 1u)) >> 16);
}

__device__ __forceinline__ unsigned int cvtpk(float a, float b) {
    unsigned int r;
    asm("v_cvt_pk_bf16_f32 %0, %1, %2" : "=v"(r) : "v"(a), "v"(b));
    return r;
}

__device__ __forceinline__ bool mask_on(const unsigned char* m, int gid) {
    return (m[gid] | m[(gid >> 2) << 2]) != 0;
}

__device__ __forceinline__ int foff(int row, int g) {
    return row * 128 + (((g) ^ (row & 7)) << 4);
}

// B-panel staging: 128 rows x 64 bf16, 256-thread blocks (R10-exact)
template<int GSTRIDE>
__device__ __forceinline__ void stage_B(const unsigned short* __restrict__ gb,
                                        int k0, unsigned short* ldsB, int t)
{
    const int l = t & 63, w = t >> 6;
    const int hsub = l >> 3;
    const int csrc = ((l & 7) ^ hsub) << 3;
    #pragma unroll
    for (int i = 0; i < 4; ++i) {
        const int hbase = i * 32 + w * 8;
        const unsigned short* src = gb + (size_t)(hbase + hsub) * GSTRIDE + k0 + csrc;
        unsigned short* dst = ldsB + hbase * 64;
        __builtin_amdgcn_global_load_lds(
            (__attribute__((address_space(1))) void*)src,
            (__attribute__((address_space(3))) void*)dst, 16, 0, 0);
    }
}

// ---------------------------------------------------------------------------
// k0: WT[t][d][h] = bf16(W[t][h][d])
// ---------------------------------------------------------------------------
__global__ __launch_bounds__(256) void k0_wtrans(
    const float* __restrict__ W, unsigned short* __restrict__ WT)
{
    __shared__ float tile[128][132];
    const int t = threadIdx.x, ty = blockIdx.x;
    const float* Wt = W + (size_t)ty * 128 * 128;
    for (int it = 0; it < 16; ++it) {
        int idx = it * 256 + t;
        int h = idx >> 5, c = (idx & 31) * 4;
        *(float4*)(&tile[h][c]) = *(const float4*)(Wt + h * 128 + c);
    }
    __syncthreads();
    const int d = t >> 1, half = t & 1, h0 = half * 64;
    unsigned short* out = WT + ((size_t)ty * 128 + d) * 128 + h0;
    #pragma unroll
    for (int ch = 0; ch < 8; ++ch) {
        int h = h0 + ch * 8;
        u32x4_t o;
        o[0] = cvtpk(tile[h + 0][d], tile[h + 1][d]);
        o[1] = cvtpk(tile[h + 2][d], tile[h + 3][d]);
        o[2] = cvtpk(tile[h + 4][d], tile[h + 5][d]);
        o[3] = cvtpk(tile[h + 6][d], tile[h + 7][d]);
        *(u32x4_t*)(out + ch * 8) = o;
    }
}

// ---------------------------------------------------------------------------
// k1: typed linear (MFMA) + bias + mask + LayerNorm -> xT bf16 [B][H][N]
// (unchanged from R10)
// ---------------------------------------------------------------------------
__global__ __launch_bounds__(256) void k1_typed_ln(
    const float* __restrict__ embeds,
    const int*   __restrict__ ntype,
    const unsigned char* __restrict__ mask8,
    const unsigned short* __restrict__ WT,
    const float* __restrict__ bias,
    const float* __restrict__ gamma,
    const float* __restrict__ beta,
    unsigned short* __restrict__ xT)
{
    __shared__ unsigned short e_lds[64][136];
    __shared__ unsigned short y_lds[64][136];
    __shared__ unsigned short lists[13][64];
    __shared__ int cnt[13];
    __shared__ int grp_ty[32], grp_base[32], grp_n;
    __shared__ unsigned char msk[64];
    __shared__ float g_lds[128], be_lds[128];

    const int t   = threadIdx.x;
    const int bid = blockIdx.x;
    const int b   = bid & 7;
    const int n0  = (bid >> 3) << 6;
    const int gbase = b * 4096 + n0;
    const float* ebase = embeds + (size_t)gbase * 128;

    {
        const int n = t >> 2, q = t & 3;
        const float* src = ebase + n * 128 + q * 32;
        #pragma unroll
        for (int c = 0; c < 4; ++c) {
            f32x4_t va = *(const f32x4_t*)(src + c * 8);
            f32x4_t vb = *(const f32x4_t*)(src + c * 8 + 4);
            u32x4_t o;
            o[0] = cvtpk(va[0], va[1]); o[1] = cvtpk(va[2], va[3]);
            o[2] = cvtpk(vb[0], vb[1]); o[3] = cvtpk(vb[2], vb[3]);
            *(u32x4_t*)(&e_lds[n][q * 32 + c * 8]) = o;
        }
    }
    if (t < 128) { g_lds[t] = gamma[t]; be_lds[t] = beta[t]; }
    if (t < 64)  msk[t] = mask_on(mask8, gbase + t) ? 1 : 0;
    if (t < 13)  cnt[t] = 0;
    __syncthreads();

    if (t < 64) {
        int ty = ntype[(size_t)gbase + t];
        int slot = atomicAdd(&cnt[ty], 1);
        lists[ty][slot] = (unsigned short)t;
    }
    __syncthreads();
    if (t == 0) {
        int g = 0;
        for (int ty = 0; ty < 13; ++ty) {
            int c = cnt[ty];
            for (int base = 0; base < c; base += 16) {
                grp_ty[g] = ty; grp_base[g] = base; ++g;
            }
        }
        grp_n = g;
    }
    __syncthreads();

    const int NG   = grp_n;
    const int lane = t & 63, wv = t >> 6;
    const int fr = lane & 15, fg = lane >> 4;
    const int d0 = wv * 32;

    for (int g = 0; g < NG; ++g) {
        const int ty = grp_ty[g], base = grp_base[g];
        const int cend = cnt[ty] - 1;
        const int nodeA = lists[ty][min(base + fr, cend)];

        bf16x8_t afr[4];
        #pragma unroll
        for (int kk = 0; kk < 4; ++kk)
            afr[kk] = __builtin_bit_cast(bf16x8_t,
                *(const u32x4_t*)(&e_lds[nodeA][kk * 32 + fg * 8]));

        const unsigned short* wt = WT + (size_t)ty * 128 * 128;
        f32x4_t acc0 = f32x4_t{0.f, 0.f, 0.f, 0.f};
        f32x4_t acc1 = f32x4_t{0.f, 0.f, 0.f, 0.f};
        #pragma unroll
        for (int kk = 0; kk < 4; ++kk) {
            bf16x8_t b0 = __builtin_bit_cast(bf16x8_t,
                *(const u32x4_t*)(wt + (size_t)(d0 + fr) * 128 + kk * 32 + fg * 8));
            bf16x8_t b1 = __builtin_bit_cast(bf16x8_t,
                *(const u32x4_t*)(wt + (size_t)(d0 + 16 + fr) * 128 + kk * 32 + fg * 8));
            acc0 = __builtin_amdgcn_mfma_f32_16x16x32_bf16(afr[kk], b0, acc0, 0, 0, 0);
            acc1 = __builtin_amdgcn_mfma_f32_16x16x32_bf16(afr[kk], b1, acc1, 0, 0, 0);
        }

        const float bs0 = bias[ty * 128 + d0 + fr];
        const float bs1 = bias[ty * 128 + d0 + 16 + fr];
        #pragma unroll
        for (int j = 0; j < 4; ++j) {
            const int nd = lists[ty][min(base + fg * 4 + j, cend)];
            if (msk[nd]) {
                y_lds[nd][d0 + fr]      = f2bf(acc0[j] + bs0);
                y_lds[nd][d0 + 16 + fr] = f2bf(acc1[j] + bs1);
            } else {
                y_lds[nd][d0 + fr]      = e_lds[nd][d0 + fr];
                y_lds[nd][d0 + 16 + fr] = e_lds[nd][d0 + 16 + fr];
            }
        }
    }
    __syncthreads();

    for (int i = 0; i < 16; ++i) {
        const int n = wv + i * 4;
        unsigned int u = *(const unsigned int*)(&y_lds[n][lane * 2]);
        float vx = __builtin_bit_cast(float, u << 16);
        float vy = __builtin_bit_cast(float, u & 0xffff0000u);
        float s = vx + vy;
        float q = vx * vx + vy * vy;
        #pragma unroll
        for (int mw = 32; mw >= 1; mw >>= 1) {
            s += __shfl_xor(s, mw);
            q += __shfl_xor(q, mw);
        }
        const float mu  = s * 0.0078125f;
        const float var = q * 0.0078125f - mu * mu;
        const float r   = rsqrtf(var + 1e-5f);
        const float ox = (vx - mu) * r * g_lds[lane * 2]     + be_lds[lane * 2];
        const float oy = (vy - mu) * r * g_lds[lane * 2 + 1] + be_lds[lane * 2 + 1];
        *(unsigned int*)(&y_lds[n][lane * 2]) = cvtpk(ox, oy);
    }
    __syncthreads();

    const int nl = t & 63, hg = t >> 6;
    unsigned short* xrow = xT + (size_t)b * 128 * 4096 + n0 + nl;
    for (int i = 0; i < 32; ++i) {
        const int h = hg * 32 + i;
        xrow[(size_t)h * 4096] = y_lds[nl][h];
    }
}

// ---------------------------------------------------------------------------
// Kernel 2: pLat[nc][b][h][m] = sum_{n in half nc} adj[b][n][m]*x[b][n][h]
// R10 k2 body; grid 1024 = 8b x 64mt x 2nc; 32 steps; f32x4 partial stores.
// ---------------------------------------------------------------------------
__global__ __launch_bounds__(256) void k2_lat(
    const float* __restrict__ adj,
    const unsigned short* __restrict__ xT,
    float* __restrict__ pLat)
{
    __shared__ unsigned short Al[2][32 * 64];
    __shared__ unsigned short Bl[2][128 * 64];

    const int t   = threadIdx.x;
    const int bid = blockIdx.x;
    const int b   = bid & 7;
    const int r   = bid >> 3;              // 0..127
    const int m0  = (r & 63) << 5;
    const int nc  = r >> 6;                // 0..1
    const int nbase = nc << 11;            // nc * 2048
    const float* adjb = adj + (size_t)b * 4096 * 2048;
    const unsigned short* xb = xT + (size_t)b * 128 * 4096;

    const int lane = t & 63, wv = t >> 6;
    const int wm = wv & 1, wh = wv >> 1;

    const int a_kp = t >> 3;
    const int a_m  = (t & 7) << 2;

    const int fr = lane & 15, fg = lane >> 4;
    int offA[2], offB[4][2];
    #pragma unroll
    for (int kk = 0; kk < 2; ++kk) offA[kk] = foff(wm * 16 + fr, kk * 4 + fg);
    #pragma unroll
    for (int j = 0; j < 4; ++j)
        #pragma unroll
        for (int kk = 0; kk < 2; ++kk)
            offB[j][kk] = foff(wh * 64 + j * 16 + fr, kk * 4 + fg);

    f32x4_t ar0, ar1;
    auto LOAD_A = [&](int k0) {
        const float* p = adjb + (size_t)(nbase + k0 + a_kp * 2) * 2048 + m0 + a_m;
        ar0 = *(const f32x4_t*)(p);
        ar1 = *(const f32x4_t*)(p + 2048);
    };
    auto WRITE_A = [&](int buf) {
        const int g = a_kp >> 2, wrd = a_kp & 3;
        #pragma unroll
        for (int j = 0; j < 4; ++j) {
            const int m = a_m + j;
            unsigned int pk = cvtpk(ar0[j], ar1[j]);
            *(unsigned int*)((char*)(&Al[buf][0]) + m * 128 + ((g ^ (m & 7)) << 4) + wrd * 4) = pk;
        }
    };

    f32x4_t acc[4];
    #pragma unroll
    for (int j = 0; j < 4; ++j) acc[j] = f32x4_t{0.f, 0.f, 0.f, 0.f};

    LOAD_A(0);
    stage_B<4096>(xb, nbase, &Bl[0][0], t);
    WRITE_A(0);
    __syncthreads();

    for (int s = 0; s < 32; ++s) {
        const int buf = s & 1;
        if (s < 31) {
            LOAD_A((s + 1) * 64);
            stage_B<4096>(xb, nbase + (s + 1) * 64, &Bl[buf ^ 1][0], t);
        }
        bf16x8_t af[2];
        #pragma unroll
        for (int kk = 0; kk < 2; ++kk)
            af[kk] = __builtin_bit_cast(bf16x8_t,
                *(const u32x4_t*)((const char*)(&Al[buf][0]) + offA[kk]));
        #pragma unroll
        for (int j = 0; j < 4; ++j) {
            #pragma unroll
            for (int kk = 0; kk < 2; ++kk) {
                bf16x8_t bfj = __builtin_bit_cast(bf16x8_t,
                    *(const u32x4_t*)((const char*)(&Bl[buf][0]) + offB[j][kk]));
                acc[j] = __builtin_amdgcn_mfma_f32_16x16x32_bf16(af[kk], bfj, acc[j], 0, 0, 0);
            }
        }
        if (s < 31) WRITE_A(buf ^ 1);
        __syncthreads();
    }

    // f32x4 partial store (R8-proven pattern): pLat[nc][b][col][mrow..mrow+3]
    float* pb = pLat + (size_t)(nc * 8 + b) * 128 * 2048;
    const int mrow = m0 + wm * 16 + (lane >> 4) * 4;
    #pragma unroll
    for (int j = 0; j < 4; ++j) {
        int col = wh * 64 + j * 16 + fr;
        *(f32x4_t*)(pb + (size_t)col * 2048 + mrow) = acc[j];
    }
}

// latT = bf16(pLat[0] + pLat[1]) — flat over 2.1M elems, grid 2048
__global__ __launch_bounds__(256) void k2_red(
    const float* __restrict__ pLat,
    unsigned short* __restrict__ latT)
{
    const size_t i4 = ((size_t)blockIdx.x * 256 + threadIdx.x) * 4;
    f32x4_t s = *(const f32x4_t*)(pLat + i4);
    s += *(const f32x4_t*)(pLat + i4 + (size_t)2097152);
    u32x2_t o;
    o[0] = cvtpk(s[0], s[1]);
    o[1] = cvtpk(s[2], s[3]);
    *(u32x2_t*)(latT + i4) = o;
}

// ---------------------------------------------------------------------------
// Kernel 3 (R10-exact): ret[b][n][h] = sum_m adj[b][n][m] * latT[b][h][m]
// ---------------------------------------------------------------------------
__global__ __launch_bounds__(256) void k3_ret(
    const float* __restrict__ adj,
    const unsigned short* __restrict__ latT,
    float* __restrict__ ret)
{
    __shared__ unsigned short Al[2][32 * 64];
    __shared__ unsigned short Bl[2][128 * 64];

    const int t   = threadIdx.x;
    const int bid = blockIdx.x;
    const int b   = bid & 7;
    const int n0  = (bid >> 3) << 5;
    const float* adjb = adj + (size_t)b * 4096 * 2048;
    const unsigned short* lb = latT + (size_t)b * 128 * 2048;

    const int lane = t & 63, wv = t >> 6;
    const int wn = wv & 1, wh = wv >> 1;

    const int a_r = t >> 3;
    const int a_c = t & 7;

    const int fr = lane & 15, fg = lane >> 4;
    int offA[2], offB[4][2];
    #pragma unroll
    for (int kk = 0; kk < 2; ++kk) offA[kk] = foff(wn * 16 + fr, kk * 4 + fg);
    #pragma unroll
    for (int j = 0; j < 4; ++j)
        #pragma unroll
        for (int kk = 0; kk < 2; ++kk)
            offB[j][kk] = foff(wh * 64 + j * 16 + fr, kk * 4 + fg);

    f32x4_t ar0, ar1;
    auto LOAD_A = [&](int k0) {
        const float* p = adjb + (size_t)(n0 + a_r) * 2048 + k0 + a_c * 8;
        ar0 = *(const f32x4_t*)(p);
        ar1 = *(const f32x4_t*)(p + 4);
    };
    auto WRITE_A = [&](int buf) {
        u32x4_t pk;
        pk[0] = cvtpk(ar0[0], ar0[1]);
        pk[1] = cvtpk(ar0[2], ar0[3]);
        pk[2] = cvtpk(ar1[0], ar1[1]);
        pk[3] = cvtpk(ar1[2], ar1[3]);
        *(u32x4_t*)((char*)(&Al[buf][0]) + a_r * 128 + ((a_c ^ (a_r & 7)) << 4)) = pk;
    };

    f32x4_t acc[4];
    #pragma unroll
    for (int j = 0; j < 4; ++j) acc[j] = f32x4_t{0.f, 0.f, 0.f, 0.f};

    LOAD_A(0);
    stage_B<2048>(lb, 0, &Bl[0][0], t);
    WRITE_A(0);
    __syncthreads();

    for (int s = 0; s < 32; ++s) {
        const int buf = s & 1;
        if (s < 31) {
            LOAD_A((s + 1) * 64);
            stage_B<2048>(lb, (s + 1) * 64, &Bl[buf ^ 1][0], t);
        }
        bf16x8_t af[2];
        #pragma unroll
        for (int kk = 0; kk < 2; ++kk)
            af[kk] = __builtin_bit_cast(bf16x8_t,
                *(const u32x4_t*)((const char*)(&Al[buf][0]) + offA[kk]));
        #pragma unroll
        for (int j = 0; j < 4; ++j) {
            #pragma unroll
            for (int kk = 0; kk < 2; ++kk) {
                bf16x8_t bfj = __builtin_bit_cast(bf16x8_t,
                    *(const u32x4_t*)((const char*)(&Bl[buf][0]) + offB[j][kk]));
                acc[j] = __builtin_amdgcn_mfma_f32_16x16x32_bf16(af[kk], bfj, acc[j], 0, 0, 0);
            }
        }
        if (s < 31) WRITE_A(buf ^ 1);
        __syncthreads();
    }

    const int nrow = n0 + wn * 16 + (lane >> 4) * 4;
    #pragma unroll
    for (int j = 0; j < 4; ++j) {
        int col = wh * 64 + j * 16 + fr;
        #pragma unroll
        for (int jj = 0; jj < 4; ++jj) {
            ret[((size_t)b * 4096 + nrow + jj) * 128 + col] = acc[j][jj];
        }
    }
}

// ---------------------------------------------------------------------------
extern "C" void kernel_launch(void* const* d_in, const int* in_sizes, int n_in,
                              void* d_out, int out_size, void* d_ws, size_t ws_size,
                              hipStream_t stream) {
    const float* adj    = (const float*)d_in[0];
    const float* embeds = (const float*)d_in[1];
    const int*   ntype  = (const int*)d_in[2];
    const unsigned char* mask8 = (const unsigned char*)d_in[3];
    const float* W      = (const float*)d_in[4];
    const float* bias   = (const float*)d_in[5];
    const float* gamma  = (const float*)d_in[6];
    const float* beta   = (const float*)d_in[7];
    float* ret = (float*)d_out;

    unsigned short* xT   = (unsigned short*)d_ws;                   // 8.39 MB
    unsigned short* latT = xT + (size_t)8 * 128 * 4096;             // 4.19 MB
    unsigned short* WT   = latT + (size_t)8 * 128 * 2048;           // 0.43 MB
    float* pLat = (float*)(WT + (size_t)13 * 128 * 128);            // 16.78 MB
    // ws needed: 29.8 MB

    hipLaunchKernelGGL(k0_wtrans, dim3(13), dim3(256), 0, stream, W, WT);
    hipLaunchKernelGGL(k1_typed_ln, dim3(512), dim3(256), 0, stream,
                       embeds, ntype, mask8, WT, bias, gamma, beta, xT);
    hipLaunchKernelGGL(k2_lat, dim3(1024), dim3(256), 0, stream, adj, xT, pLat);
    hipLaunchKernelGGL(k2_red, dim3(2048), dim3(256), 0, stream, pLat, latT);
    hipLaunchKernelGGL(k3_ret, dim3(1024), dim3(256), 0, stream, adj, latT, ret);
}

// Round 17
// 169.361 us; speedup vs baseline: 2.3080x; 1.1010x over previous
//
#include <hip/hip_runtime.h>
#include <stdint.h>
#include <stddef.h>

// ---------------------------------------------------------------------------
// HHGNN. R17 vs R10 (167.2us champion; R16 split-K x2 at BM=32 regressed ->
// occupancy theory dead). Remaining mechanism: k2 reads 128B per 8KB-strided
// adj row (BM=32) -> ~53% DRAM efficiency (R14: 268MB in 80us = 3.35TB/s);
// k3's contiguous rows run at floor. ONE lever: slice width 128B -> 512B:
// k2 = R8's proven BM=128 x 4nc geometry VERBATIM (grid 512, 2 blocks/CU,
// same occupancy as R10-k2 — isolates the slice-width variable), fp32
// partials + 4-way reduce (R8's k2_red verbatim).
// k0/k1/k3 byte-identical to R10.
// ws: xT 8.39 + latT 4.19 + WT 0.43 + pLat 33.55 = 46.6MB.
// ---------------------------------------------------------------------------

typedef float    f32x4_t  __attribute__((ext_vector_type(4)));
typedef __bf16   bf16x8_t __attribute__((ext_vector_type(8)));
typedef unsigned int u32x4_t __attribute__((ext_vector_type(4)));
typedef unsigned int u32x2_t __attribute__((ext_vector_type(2)));

__device__ __forceinline__ unsigned short f2bf(float f) {
    union { float f; unsigned int u; } v; v.f = f;
    unsigned int u = v.u;
    return (unsigned short)((u + 0x7FFFu + ((u >> 16) & 1u)) >> 16);
}

__device__ __forceinline__ unsigned int cvtpk(float a, float b) {
    unsigned int r;
    asm("v_cvt_pk_bf16_f32 %0, %1, %2" : "=v"(r) : "v"(a), "v"(b));
    return r;
}

__device__ __forceinline__ bool mask_on(const unsigned char* m, int gid) {
    return (m[gid] | m[(gid >> 2) << 2]) != 0;
}

__device__ __forceinline__ int foff(int row, int g) {
    return row * 128 + (((g) ^ (row & 7)) << 4);
}

// B-panel staging: 128 rows x 64 bf16, 256-thread blocks
template<int GSTRIDE>
__device__ __forceinline__ void stage_B(const unsigned short* __restrict__ gb,
                                        int k0, unsigned short* ldsB, int t)
{
    const int l = t & 63, w = t >> 6;
    const int hsub = l >> 3;
    const int csrc = ((l & 7) ^ hsub) << 3;
    #pragma unroll
    for (int i = 0; i < 4; ++i) {
        const int hbase = i * 32 + w * 8;
        const unsigned short* src = gb + (size_t)(hbase + hsub) * GSTRIDE + k0 + csrc;
        unsigned short* dst = ldsB + hbase * 64;
        __builtin_amdgcn_global_load_lds(
            (__attribute__((address_space(1))) void*)src,
            (__attribute__((address_space(3))) void*)dst, 16, 0, 0);
    }
}

// ---------------------------------------------------------------------------
// k0: WT[t][d][h] = bf16(W[t][h][d])
// ---------------------------------------------------------------------------
__global__ __launch_bounds__(256) void k0_wtrans(
    const float* __restrict__ W, unsigned short* __restrict__ WT)
{
    __shared__ float tile[128][132];
    const int t = threadIdx.x, ty = blockIdx.x;
    const float* Wt = W + (size_t)ty * 128 * 128;
    for (int it = 0; it < 16; ++it) {
        int idx = it * 256 + t;
        int h = idx >> 5, c = (idx & 31) * 4;
        *(float4*)(&tile[h][c]) = *(const float4*)(Wt + h * 128 + c);
    }
    __syncthreads();
    const int d = t >> 1, half = t & 1, h0 = half * 64;
    unsigned short* out = WT + ((size_t)ty * 128 + d) * 128 + h0;
    #pragma unroll
    for (int ch = 0; ch < 8; ++ch) {
        int h = h0 + ch * 8;
        u32x4_t o;
        o[0] = cvtpk(tile[h + 0][d], tile[h + 1][d]);
        o[1] = cvtpk(tile[h + 2][d], tile[h + 3][d]);
        o[2] = cvtpk(tile[h + 4][d], tile[h + 5][d]);
        o[3] = cvtpk(tile[h + 6][d], tile[h + 7][d]);
        *(u32x4_t*)(out + ch * 8) = o;
    }
}

// ---------------------------------------------------------------------------
// k1: typed linear (MFMA) + bias + mask + LayerNorm -> xT bf16 [B][H][N]
// (unchanged from R10)
// ---------------------------------------------------------------------------
__global__ __launch_bounds__(256) void k1_typed_ln(
    const float* __restrict__ embeds,
    const int*   __restrict__ ntype,
    const unsigned char* __restrict__ mask8,
    const unsigned short* __restrict__ WT,
    const float* __restrict__ bias,
    const float* __restrict__ gamma,
    const float* __restrict__ beta,
    unsigned short* __restrict__ xT)
{
    __shared__ unsigned short e_lds[64][136];
    __shared__ unsigned short y_lds[64][136];
    __shared__ unsigned short lists[13][64];
    __shared__ int cnt[13];
    __shared__ int grp_ty[32], grp_base[32], grp_n;
    __shared__ unsigned char msk[64];
    __shared__ float g_lds[128], be_lds[128];

    const int t   = threadIdx.x;
    const int bid = blockIdx.x;
    const int b   = bid & 7;
    const int n0  = (bid >> 3) << 6;
    const int gbase = b * 4096 + n0;
    const float* ebase = embeds + (size_t)gbase * 128;

    {
        const int n = t >> 2, q = t & 3;
        const float* src = ebase + n * 128 + q * 32;
        #pragma unroll
        for (int c = 0; c < 4; ++c) {
            f32x4_t va = *(const f32x4_t*)(src + c * 8);
            f32x4_t vb = *(const f32x4_t*)(src + c * 8 + 4);
            u32x4_t o;
            o[0] = cvtpk(va[0], va[1]); o[1] = cvtpk(va[2], va[3]);
            o[2] = cvtpk(vb[0], vb[1]); o[3] = cvtpk(vb[2], vb[3]);
            *(u32x4_t*)(&e_lds[n][q * 32 + c * 8]) = o;
        }
    }
    if (t < 128) { g_lds[t] = gamma[t]; be_lds[t] = beta[t]; }
    if (t < 64)  msk[t] = mask_on(mask8, gbase + t) ? 1 : 0;
    if (t < 13)  cnt[t] = 0;
    __syncthreads();

    if (t < 64) {
        int ty = ntype[(size_t)gbase + t];
        int slot = atomicAdd(&cnt[ty], 1);
        lists[ty][slot] = (unsigned short)t;
    }
    __syncthreads();
    if (t == 0) {
        int g = 0;
        for (int ty = 0; ty < 13; ++ty) {
            int c = cnt[ty];
            for (int base = 0; base < c; base += 16) {
                grp_ty[g] = ty; grp_base[g] = base; ++g;
            }
        }
        grp_n = g;
    }
    __syncthreads();

    const int NG   = grp_n;
    const int lane = t & 63, wv = t >> 6;
    const int fr = lane & 15, fg = lane >> 4;
    const int d0 = wv * 32;

    for (int g = 0; g < NG; ++g) {
        const int ty = grp_ty[g], base = grp_base[g];
        const int cend = cnt[ty] - 1;
        const int nodeA = lists[ty][min(base + fr, cend)];

        bf16x8_t afr[4];
        #pragma unroll
        for (int kk = 0; kk < 4; ++kk)
            afr[kk] = __builtin_bit_cast(bf16x8_t,
                *(const u32x4_t*)(&e_lds[nodeA][kk * 32 + fg * 8]));

        const unsigned short* wt = WT + (size_t)ty * 128 * 128;
        f32x4_t acc0 = f32x4_t{0.f, 0.f, 0.f, 0.f};
        f32x4_t acc1 = f32x4_t{0.f, 0.f, 0.f, 0.f};
        #pragma unroll
        for (int kk = 0; kk < 4; ++kk) {
            bf16x8_t b0 = __builtin_bit_cast(bf16x8_t,
                *(const u32x4_t*)(wt + (size_t)(d0 + fr) * 128 + kk * 32 + fg * 8));
            bf16x8_t b1 = __builtin_bit_cast(bf16x8_t,
                *(const u32x4_t*)(wt + (size_t)(d0 + 16 + fr) * 128 + kk * 32 + fg * 8));
            acc0 = __builtin_amdgcn_mfma_f32_16x16x32_bf16(afr[kk], b0, acc0, 0, 0, 0);
            acc1 = __builtin_amdgcn_mfma_f32_16x16x32_bf16(afr[kk], b1, acc1, 0, 0, 0);
        }

        const float bs0 = bias[ty * 128 + d0 + fr];
        const float bs1 = bias[ty * 128 + d0 + 16 + fr];
        #pragma unroll
        for (int j = 0; j < 4; ++j) {
            const int nd = lists[ty][min(base + fg * 4 + j, cend)];
            if (msk[nd]) {
                y_lds[nd][d0 + fr]      = f2bf(acc0[j] + bs0);
                y_lds[nd][d0 + 16 + fr] = f2bf(acc1[j] + bs1);
            } else {
                y_lds[nd][d0 + fr]      = e_lds[nd][d0 + fr];
                y_lds[nd][d0 + 16 + fr] = e_lds[nd][d0 + 16 + fr];
            }
        }
    }
    __syncthreads();

    for (int i = 0; i < 16; ++i) {
        const int n = wv + i * 4;
        unsigned int u = *(const unsigned int*)(&y_lds[n][lane * 2]);
        float vx = __builtin_bit_cast(float, u << 16);
        float vy = __builtin_bit_cast(float, u & 0xffff0000u);
        float s = vx + vy;
        float q = vx * vx + vy * vy;
        #pragma unroll
        for (int mw = 32; mw >= 1; mw >>= 1) {
            s += __shfl_xor(s, mw);
            q += __shfl_xor(q, mw);
        }
        const float mu  = s * 0.0078125f;
        const float var = q * 0.0078125f - mu * mu;
        const float r   = rsqrtf(var + 1e-5f);
        const float ox = (vx - mu) * r * g_lds[lane * 2]     + be_lds[lane * 2];
        const float oy = (vy - mu) * r * g_lds[lane * 2 + 1] + be_lds[lane * 2 + 1];
        *(unsigned int*)(&y_lds[n][lane * 2]) = cvtpk(ox, oy);
    }
    __syncthreads();

    const int nl = t & 63, hg = t >> 6;
    unsigned short* xrow = xT + (size_t)b * 128 * 4096 + n0 + nl;
    for (int i = 0; i < 32; ++i) {
        const int h = hg * 32 + i;
        xrow[(size_t)h * 4096] = y_lds[nl][h];
    }
}

// ---------------------------------------------------------------------------
// Kernel 2 (R8-proven): pLat[nc][b][h][m] = sum_{n in nc} adj[n][m]*x[n][h]
// grid 512 = 8b x 16mt(128m) x 4nc(1024n). 4 waves (2m x 2h), BK=64,
// 16 steps. A-slices 512B/row (4x wider than BM=32).
// ---------------------------------------------------------------------------
__global__ __launch_bounds__(256) void k2_lat(
    const float* __restrict__ adj,
    const unsigned short* __restrict__ xT,
    float* __restrict__ pLat)
{
    __shared__ unsigned short Al[2][128 * 64];   // [m][k] bf16
    __shared__ unsigned short Bl[2][128 * 64];   // [h][k] bf16

    const int t   = threadIdx.x;
    const int bid = blockIdx.x;
    const int b   = bid & 7;
    const int r   = bid >> 3;
    const int m0  = (r & 15) << 7;
    const int nc  = r >> 4;
    const int nbase = nc << 10;
    const float* adjb = adj + (size_t)b * 4096 * 2048;
    const unsigned short* xb = xT + (size_t)b * 128 * 4096;

    const int lane = t & 63, wv = t >> 6;
    const int wm = wv & 1, wh = wv >> 1;

    const int a_kp = t >> 3;        // k-pair 0..31
    const int a_mc = t & 7;         // m sub-chunk (4 m's), x4 c-iters

    const int fr = lane & 15, fg = lane >> 4;
    int offA[4][2], offB[4][2];
    #pragma unroll
    for (int f = 0; f < 4; ++f)
        #pragma unroll
        for (int kk = 0; kk < 2; ++kk) {
            offA[f][kk] = foff(wm * 64 + f * 16 + fr, kk * 4 + fg);
            offB[f][kk] = foff(wh * 64 + f * 16 + fr, kk * 4 + fg);
        }

    f32x4_t ar0[4], ar1[4];
    auto LOAD_A = [&](int k0) {      // k0 absolute within batch
        #pragma unroll
        for (int c = 0; c < 4; ++c) {
            const float* p = adjb + (size_t)(k0 + 2 * a_kp) * 2048 + m0 + c * 32 + a_mc * 4;
            ar0[c] = *(const f32x4_t*)(p);
            ar1[c] = *(const f32x4_t*)(p + 2048);
        }
    };
    const int awg = a_kp >> 2, awd = a_kp & 3;
    auto WRITE_A = [&](int buf) {
        #pragma unroll
        for (int c = 0; c < 4; ++c)
            #pragma unroll
            for (int j = 0; j < 4; ++j) {
                const int m = c * 32 + a_mc * 4 + j;
                *(unsigned int*)((char*)(&Al[buf][0]) + m * 128
                    + ((awg ^ (m & 7)) << 4) + awd * 4) = cvtpk(ar0[c][j], ar1[c][j]);
            }
    };

    f32x4_t acc[4][4];
    #pragma unroll
    for (int i = 0; i < 4; ++i)
        #pragma unroll
        for (int j = 0; j < 4; ++j) acc[i][j] = f32x4_t{0.f, 0.f, 0.f, 0.f};

    LOAD_A(nbase);
    stage_B<4096>(xb, nbase, &Bl[0][0], t);
    WRITE_A(0);
    __syncthreads();

    for (int s = 0; s < 16; ++s) {
        const int buf = s & 1;
        if (s < 15) {
            LOAD_A(nbase + (s + 1) * 64);
            stage_B<4096>(xb, nbase + (s + 1) * 64, &Bl[buf ^ 1][0], t);
        }
        bf16x8_t af[4][2];
        #pragma unroll
        for (int mf = 0; mf < 4; ++mf)
            #pragma unroll
            for (int kk = 0; kk < 2; ++kk)
                af[mf][kk] = __builtin_bit_cast(bf16x8_t,
                    *(const u32x4_t*)((const char*)(&Al[buf][0]) + offA[mf][kk]));
        #pragma unroll
        for (int hf = 0; hf < 4; ++hf) {
            bf16x8_t bfr[2];
            #pragma unroll
            for (int kk = 0; kk < 2; ++kk)
                bfr[kk] = __builtin_bit_cast(bf16x8_t,
                    *(const u32x4_t*)((const char*)(&Bl[buf][0]) + offB[hf][kk]));
            #pragma unroll
            for (int mf = 0; mf < 4; ++mf)
                #pragma unroll
                for (int kk = 0; kk < 2; ++kk)
                    acc[mf][hf] = __builtin_amdgcn_mfma_f32_16x16x32_bf16(
                        af[mf][kk], bfr[kk], acc[mf][hf], 0, 0, 0);
        }
        if (s < 15) WRITE_A(buf ^ 1);
        __syncthreads();
    }

    float* pb = pLat + (size_t)(nc * 8 + b) * 128 * 2048;
    #pragma unroll
    for (int mf = 0; mf < 4; ++mf) {
        const int mrow = m0 + wm * 64 + mf * 16 + (lane >> 4) * 4;
        #pragma unroll
        for (int hf = 0; hf < 4; ++hf) {
            const int col = wh * 64 + hf * 16 + fr;
            *(f32x4_t*)(pb + (size_t)col * 2048 + mrow) = acc[mf][hf];
        }
    }
}

// latT[b][h][m] = bf16( sum_nc pLat[nc][b][h][m] ) — flat, grid 2048
__global__ __launch_bounds__(256) void k2_red(
    const float* __restrict__ pLat,
    unsigned short* __restrict__ latT)
{
    const size_t i4 = ((size_t)blockIdx.x * 256 + threadIdx.x) * 4;
    f32x4_t s = *(const f32x4_t*)(pLat + i4);
    #pragma unroll
    for (int nc = 1; nc < 4; ++nc)
        s += *(const f32x4_t*)(pLat + i4 + (size_t)nc * 2097152);
    u32x2_t o;
    o[0] = cvtpk(s[0], s[1]);
    o[1] = cvtpk(s[2], s[3]);
    *(u32x2_t*)(latT + i4) = o;
}

// ---------------------------------------------------------------------------
// Kernel 3 (R10-exact): ret[b][n][h] = sum_m adj[b][n][m] * latT[b][h][m]
// ---------------------------------------------------------------------------
__global__ __launch_bounds__(256) void k3_ret(
    const float* __restrict__ adj,
    const unsigned short* __restrict__ latT,
    float* __restrict__ ret)
{
    __shared__ unsigned short Al[2][32 * 64];
    __shared__ unsigned short Bl[2][128 * 64];

    const int t   = threadIdx.x;
    const int bid = blockIdx.x;
    const int b   = bid & 7;
    const int n0  = (bid >> 3) << 5;
    const float* adjb = adj + (size_t)b * 4096 * 2048;
    const unsigned short* lb = latT + (size_t)b * 128 * 2048;

    const int lane = t & 63, wv = t >> 6;
    const int wn = wv & 1, wh = wv >> 1;

    const int a_r = t >> 3;
    const int a_c = t & 7;

    const int fr = lane & 15, fg = lane >> 4;
    int offA[2], offB[4][2];
    #pragma unroll
    for (int kk = 0; kk < 2; ++kk) offA[kk] = foff(wn * 16 + fr, kk * 4 + fg);
    #pragma unroll
    for (int j = 0; j < 4; ++j)
        #pragma unroll
        for (int kk = 0; kk < 2; ++kk)
            offB[j][kk] = foff(wh * 64 + j * 16 + fr, kk * 4 + fg);

    f32x4_t ar0, ar1;
    auto LOAD_A = [&](int k0) {
        const float* p = adjb + (size_t)(n0 + a_r) * 2048 + k0 + a_c * 8;
        ar0 = *(const f32x4_t*)(p);
        ar1 = *(const f32x4_t*)(p + 4);
    };
    auto WRITE_A = [&](int buf) {
        u32x4_t pk;
        pk[0] = cvtpk(ar0[0], ar0[1]);
        pk[1] = cvtpk(ar0[2], ar0[3]);
        pk[2] = cvtpk(ar1[0], ar1[1]);
        pk[3] = cvtpk(ar1[2], ar1[3]);
        *(u32x4_t*)((char*)(&Al[buf][0]) + a_r * 128 + ((a_c ^ (a_r & 7)) << 4)) = pk;
    };

    f32x4_t acc[4];
    #pragma unroll
    for (int j = 0; j < 4; ++j) acc[j] = f32x4_t{0.f, 0.f, 0.f, 0.f};

    LOAD_A(0);
    stage_B<2048>(lb, 0, &Bl[0][0], t);
    WRITE_A(0);
    __syncthreads();

    for (int s = 0; s < 32; ++s) {
        const int buf = s & 1;
        if (s < 31) {
            LOAD_A((s + 1) * 64);
            stage_B<2048>(lb, (s + 1) * 64, &Bl[buf ^ 1][0], t);
        }
        bf16x8_t af[2];
        #pragma unroll
        for (int kk = 0; kk < 2; ++kk)
            af[kk] = __builtin_bit_cast(bf16x8_t,
                *(const u32x4_t*)((const char*)(&Al[buf][0]) + offA[kk]));
        #pragma unroll
        for (int j = 0; j < 4; ++j) {
            #pragma unroll
            for (int kk = 0; kk < 2; ++kk) {
                bf16x8_t bfj = __builtin_bit_cast(bf16x8_t,
                    *(const u32x4_t*)((const char*)(&Bl[buf][0]) + offB[j][kk]));
                acc[j] = __builtin_amdgcn_mfma_f32_16x16x32_bf16(af[kk], bfj, acc[j], 0, 0, 0);
            }
        }
        if (s < 31) WRITE_A(buf ^ 1);
        __syncthreads();
    }

    const int nrow = n0 + wn * 16 + (lane >> 4) * 4;
    #pragma unroll
    for (int j = 0; j < 4; ++j) {
        int col = wh * 64 + j * 16 + fr;
        #pragma unroll
        for (int jj = 0; jj < 4; ++jj) {
            ret[((size_t)b * 4096 + nrow + jj) * 128 + col] = acc[j][jj];
        }
    }
}

// ---------------------------------------------------------------------------
extern "C" void kernel_launch(void* const* d_in, const int* in_sizes, int n_in,
                              void* d_out, int out_size, void* d_ws, size_t ws_size,
                              hipStream_t stream) {
    const float* adj    = (const float*)d_in[0];
    const float* embeds = (const float*)d_in[1];
    const int*   ntype  = (const int*)d_in[2];
    const unsigned char* mask8 = (const unsigned char*)d_in[3];
    const float* W      = (const float*)d_in[4];
    const float* bias   = (const float*)d_in[5];
    const float* gamma  = (const float*)d_in[6];
    const float* beta   = (const float*)d_in[7];
    float* ret = (float*)d_out;

    unsigned short* xT   = (unsigned short*)d_ws;                   // 8.39 MB
    unsigned short* latT = xT + (size_t)8 * 128 * 4096;             // 4.19 MB
    unsigned short* WT   = latT + (size_t)8 * 128 * 2048;           // 0.43 MB
    float* pLat = (float*)(WT + (size_t)13 * 128 * 128);            // 33.55 MB
    // ws needed: 46.6 MB

    hipLaunchKernelGGL(k0_wtrans, dim3(13), dim3(256), 0, stream, W, WT);
    hipLaunchKernelGGL(k1_typed_ln, dim3(512), dim3(256), 0, stream,
                       embeds, ntype, mask8, WT, bias, gamma, beta, xT);
    hipLaunchKernelGGL(k2_lat, dim3(512), dim3(256), 0, stream, adj, xT, pLat);
    hipLaunchKernelGGL(k2_red, dim3(2048), dim3(256), 0, stream, pLat, latT);
    hipLaunchKernelGGL(k3_ret, dim3(1024), dim3(256), 0, stream, adj, latT, ret);
}